// Round 23
// baseline (401.141 us; speedup 1.0000x reference)
//
#include <hip/hip_runtime.h>
#include <hip/hip_bf16.h>
#include <cfloat>

static constexpr int NBAT = 16;
static constexpr int NPT  = 2048;
static constexpr int NSEG = 2;     // pass2 n-split segments
static constexpr int NRS  = 4;     // rowstats m-split segments

typedef _Float16 f16;
typedef _Float16 f16x8 __attribute__((ext_vector_type(8)));
typedef float    f32x4 __attribute__((ext_vector_type(4)));

static __device__ __forceinline__ f32x4 mfma16(f16x8 a, f16x8 b, f32x4 c){
  return __builtin_amdgcn_mfma_f32_16x16x32_f16(a, b, c, 0, 0, 0);
}
// MFMA 16x16x32 f16 layouts (gfx950, e2e-verified by round-4 pass):
//  A[16r x 32k]: lane l -> row l&15, k = (l>>4)*8 + j (16B contiguous)
//  B[32k x 16c]: lane l -> col l&15, k = (l>>4)*8 + j (16B contiguous)
//  D[16r x 16c]: lane l -> col l&15, rows (l>>4)*4 + i

static __device__ __forceinline__ unsigned pk2(float a, float b){
  typedef __fp16 fp16x2_n __attribute__((ext_vector_type(2)));
  fp16x2_n t = __builtin_amdgcn_cvt_pkrtz(a, b);
  union { fp16x2_n h; unsigned u; } cv; cv.h = t; return cv.u;
}

// ---- weight arena offsets (halfs) ----
static constexpr long OFF_M1W1 = 0;              // [128][128]
static constexpr long OFF_M2W0A= 16384;          // [128][128] (cols 0..127 of [128][256])
static constexpr long OFF_M2W1 = 32768;          // [128][128]
static constexpr long OFF_M3W0 = 49152;          // [512][384]
static constexpr long OFF_M3W1 = 245760;         // [1024][512]
static constexpr long OFF_SA   = 770048;         // per-L: wq[32][128], wv[128][128], wt[128][128]
static constexpr long SA_STRIDE= 36864;
static constexpr long WTOT     = OFF_SA + 3*SA_STRIDE;   // 880,640 halfs

// ---------------------------------------------------------------------------
// weight fp32 -> fp16 conversion into arena (one launch)
// ---------------------------------------------------------------------------
__global__ __launch_bounds__(256) void k_wconv(
    const float* m1w1, const float* m2w0, const float* m2w1,
    const float* m3w0, const float* m3w1,
    const float* wq0, const float* wv0, const float* wt0,
    const float* wq1, const float* wv1, const float* wt1,
    const float* wq2, const float* wv2, const float* wt2,
    f16* W)
{
  long t = (long)blockIdx.x*256 + threadIdx.x;
  if (t >= WTOT) return;
  float v;
  if      (t < OFF_M2W0A) v = m1w1[t];
  else if (t < OFF_M2W1) { long u = t-OFF_M2W0A; v = m2w0[(u>>7)*256 + (u&127)]; }
  else if (t < OFF_M3W0)  v = m2w1[t-OFF_M2W1];
  else if (t < OFF_M3W1)  v = m3w0[t-OFF_M3W0];
  else if (t < OFF_SA)    v = m3w1[t-OFF_M3W1];
  else {
    long u = t - OFF_SA; int L = (int)(u / SA_STRIDE); long r = u % SA_STRIDE;
    const float* wq = (L==0)?wq0:(L==1)?wq1:wq2;
    const float* wv = (L==0)?wv0:(L==1)?wv1:wv2;
    const float* wt = (L==0)?wt0:(L==1)?wt1:wt2;
    if (r < 4096) v = wq[r]; else if (r < 20480) v = wv[r-4096]; else v = wt[r-20480];
  }
  W[t] = (f16)v;
}

// ---------------------------------------------------------------------------
// FUSED mlp1: h1 tile computed in LDS (K=3 pointwise), then l1 GEMM.
// ---------------------------------------------------------------------------
__global__ __launch_bounds__(256) void k_mlp1f(
    const float* __restrict__ in, const float* __restrict__ w0,
    const float* __restrict__ b0,
    const f16* __restrict__ W1, const float* __restrict__ b1,
    f16* __restrict__ lfT)
{
  __shared__ __align__(16) f16 Hs[64][136];   // hidden tile, full K=128
  __shared__ __align__(16) f16 Wsh[64][72];
  const int b = blockIdx.y, n0 = blockIdx.x*64;
  const int tid = threadIdx.x, lane = tid & 63, w = tid >> 6;
  const int lr = lane & 15, lg = lane >> 4;
  const int wn = w>>1, wo = w&1;
  for (int e = tid; e < 64*128; e += 256){
    int r = e >> 7, o = e & 127;
    const float* ip = in + ((long)b*NPT + n0 + r)*3;
    float v = b0[o] + w0[o*3]*ip[0] + w0[o*3+1]*ip[1] + w0[o*3+2]*ip[2];
    Hs[r][o] = (f16)fmaxf(v, 0.f);
  }
  __syncthreads();
  f32x4 acc[2][2][2];
  #pragma unroll
  for (int oh=0;oh<2;++oh)
    #pragma unroll
    for (int ni=0;ni<2;++ni)
      #pragma unroll
      for (int oi=0;oi<2;++oi) acc[oh][ni][oi] = (f32x4){0,0,0,0};

  #pragma unroll
  for (int k0=0;k0<128;k0+=64){
    #pragma unroll
    for (int oh=0;oh<2;++oh){
      for (int g=tid; g<512; g+=256){
        int r=g>>3, s=g&7;
        *(float4*)&Wsh[r][s*8] = *(const float4*)(W1 + (long)(oh*64+r)*128 + k0 + s*8);
      }
      __syncthreads();
      #pragma unroll
      for (int ks=0;ks<2;++ks){
        f16x8 a[2], bf[2];
        #pragma unroll
        for (int ni=0;ni<2;++ni) a[ni] = *(const f16x8*)&Hs[wn*32+ni*16+lr][k0+ks*32+lg*8];
        #pragma unroll
        for (int oi=0;oi<2;++oi) bf[oi] = *(const f16x8*)&Wsh[wo*32+oi*16+lr][ks*32+lg*8];
        #pragma unroll
        for (int ni=0;ni<2;++ni)
          #pragma unroll
          for (int oi=0;oi<2;++oi) acc[oh][ni][oi] = mfma16(a[ni], bf[oi], acc[oh][ni][oi]);
      }
      __syncthreads();
    }
  }
  #pragma unroll
  for (int oh=0;oh<2;++oh)
    #pragma unroll
    for (int ni=0;ni<2;++ni)
      #pragma unroll
      for (int oi=0;oi<2;++oi){
        const int oc = oh*64 + wo*32 + oi*16 + lr;
        const float bi = b1[oc];
        #pragma unroll
        for (int i=0;i<4;++i){
          const int nn = n0 + wn*32 + ni*16 + lg*4 + i;
          lfT[((long)b*NPT + nn)*128 + oc] = (f16)(acc[oh][ni][oi][i] + bi);
        }
      }
}

// ---------------------------------------------------------------------------
// FUSED mlp2: GEMM0 (lfT -> h, relu, gc bias) into LDS, then GEMM1.
// ---------------------------------------------------------------------------
__global__ __launch_bounds__(256) void k_mlp2f(
    const f16* __restrict__ W0, const float* __restrict__ gc,
    const f16* __restrict__ W1, const float* __restrict__ b1,
    const f16* __restrict__ lfT, f16* __restrict__ featT)
{
  __shared__ __align__(16) f16 Xs[64][72];
  __shared__ __align__(16) f16 Hs[64][136];
  __shared__ __align__(16) f16 Wsh[64][72];
  const int b = blockIdx.y, n0 = blockIdx.x*64;
  const int tid = threadIdx.x, lane = tid & 63, w = tid >> 6;
  const int lr = lane & 15, lg = lane >> 4;
  const int wn = w>>1, wo = w&1;
  const f16* Xb = lfT + (long)b*NPT*128;
  f32x4 acc[2][2][2];
  #pragma unroll
  for (int oh=0;oh<2;++oh)
    #pragma unroll
    for (int ni=0;ni<2;++ni)
      #pragma unroll
      for (int oi=0;oi<2;++oi) acc[oh][ni][oi] = (f32x4){0,0,0,0};

  #pragma unroll
  for (int k0=0;k0<128;k0+=64){
    for (int g=tid; g<512; g+=256){
      int r=g>>3, s=g&7;
      *(float4*)&Xs[r][s*8] = *(const float4*)(Xb + (long)(n0+r)*128 + k0 + s*8);
    }
    #pragma unroll
    for (int oh=0;oh<2;++oh){
      for (int g=tid; g<512; g+=256){
        int r=g>>3, s=g&7;
        *(float4*)&Wsh[r][s*8] = *(const float4*)(W0 + (long)(oh*64+r)*128 + k0 + s*8);
      }
      __syncthreads();
      #pragma unroll
      for (int ks=0;ks<2;++ks){
        f16x8 a[2], bf[2];
        #pragma unroll
        for (int ni=0;ni<2;++ni) a[ni] = *(const f16x8*)&Xs[wn*32+ni*16+lr][ks*32+lg*8];
        #pragma unroll
        for (int oi=0;oi<2;++oi) bf[oi] = *(const f16x8*)&Wsh[wo*32+oi*16+lr][ks*32+lg*8];
        #pragma unroll
        for (int ni=0;ni<2;++ni)
          #pragma unroll
          for (int oi=0;oi<2;++oi) acc[oh][ni][oi] = mfma16(a[ni], bf[oi], acc[oh][ni][oi]);
      }
      __syncthreads();
    }
  }
  #pragma unroll
  for (int oh=0;oh<2;++oh)
    #pragma unroll
    for (int ni=0;ni<2;++ni)
      #pragma unroll
      for (int oi=0;oi<2;++oi){
        const int oc = oh*64 + wo*32 + oi*16 + lr;
        const float bi = gc[b*128 + oc];
        #pragma unroll
        for (int i=0;i<4;++i){
          const int rl = wn*32 + ni*16 + lg*4 + i;
          Hs[rl][oc] = (f16)fmaxf(acc[oh][ni][oi][i] + bi, 0.f);
        }
      }
  __syncthreads();

  #pragma unroll
  for (int oh=0;oh<2;++oh)
    #pragma unroll
    for (int ni=0;ni<2;++ni)
      #pragma unroll
      for (int oi=0;oi<2;++oi) acc[oh][ni][oi] = (f32x4){0,0,0,0};
  #pragma unroll
  for (int k0=0;k0<128;k0+=64){
    #pragma unroll
    for (int oh=0;oh<2;++oh){
      for (int g=tid; g<512; g+=256){
        int r=g>>3, s=g&7;
        *(float4*)&Wsh[r][s*8] = *(const float4*)(W1 + (long)(oh*64+r)*128 + k0 + s*8);
      }
      __syncthreads();
      #pragma unroll
      for (int ks=0;ks<2;++ks){
        f16x8 a[2], bf[2];
        #pragma unroll
        for (int ni=0;ni<2;++ni) a[ni] = *(const f16x8*)&Hs[wn*32+ni*16+lr][k0+ks*32+lg*8];
        #pragma unroll
        for (int oi=0;oi<2;++oi) bf[oi] = *(const f16x8*)&Wsh[wo*32+oi*16+lr][ks*32+lg*8];
        #pragma unroll
        for (int ni=0;ni<2;++ni)
          #pragma unroll
          for (int oi=0;oi<2;++oi) acc[oh][ni][oi] = mfma16(a[ni], bf[oi], acc[oh][ni][oi]);
      }
      __syncthreads();
    }
  }
  #pragma unroll
  for (int oh=0;oh<2;++oh)
    #pragma unroll
    for (int ni=0;ni<2;++ni)
      #pragma unroll
      for (int oi=0;oi<2;++oi){
        const int oc = oh*64 + wo*32 + oi*16 + lr;
        const float bi = b1[oc];
        #pragma unroll
        for (int i=0;i<4;++i){
          const int nn = n0 + wn*32 + ni*16 + lg*4 + i;
          featT[((long)b*NPT + nn)*128 + oc] = (f16)(acc[oh][ni][oi][i] + bi);
        }
      }
}

// ---------------------------------------------------------------------------
// 128x128-tile GEMM (4 waves as 2x2, each wave 64x64, acc[4][4]).
// ---------------------------------------------------------------------------
template<bool RELU>
__global__ __launch_bounds__(256, 4) void gemm128(
    const f16* __restrict__ W, const float* __restrict__ bias,
    const f16* __restrict__ XT, int xrs,
    f16* __restrict__ OUT, int ors, int K)
{
  __shared__ __align__(16) f16 Xs[128][72];
  __shared__ __align__(16) f16 Wsh[128][72];
  const int b  = blockIdx.z;
  const int n0 = blockIdx.x * 128;
  const int o0 = blockIdx.y * 128;
  const int tid = threadIdx.x, lane = tid & 63, w = tid >> 6;
  const int lr = lane & 15, lg = lane >> 4;
  const int wn = w >> 1, wo = w & 1;
  const f16* Xb = XT + (long)b*NPT*xrs;
  f32x4 acc[4][4];
  #pragma unroll
  for (int ni=0;ni<4;++ni)
    #pragma unroll
    for (int oi=0;oi<4;++oi) acc[ni][oi] = (f32x4){0,0,0,0};

  for (int k0=0; k0<K; k0+=64){
    #pragma unroll
    for (int g = tid; g < 1024; g += 256){
      int r = g>>3, s = g&7;
      *(float4*)&Xs[r][s*8]  = *(const float4*)(Xb + (long)(n0+r)*xrs + k0 + s*8);
      *(float4*)&Wsh[r][s*8] = *(const float4*)(W + (long)(o0+r)*K + k0 + s*8);
    }
    __syncthreads();
    #pragma unroll
    for (int ks=0; ks<2; ++ks){
      f16x8 a[4], bf[4];
      #pragma unroll
      for (int ni=0;ni<4;++ni) a[ni]  = *(const f16x8*)&Xs[wn*64 + ni*16 + lr][ks*32 + lg*8];
      #pragma unroll
      for (int oi=0;oi<4;++oi) bf[oi] = *(const f16x8*)&Wsh[wo*64 + oi*16 + lr][ks*32 + lg*8];
      #pragma unroll
      for (int ni=0;ni<4;++ni)
        #pragma unroll
        for (int oi=0;oi<4;++oi) acc[ni][oi] = mfma16(a[ni], bf[oi], acc[ni][oi]);
    }
    __syncthreads();
  }
  #pragma unroll
  for (int ni=0;ni<4;++ni)
    #pragma unroll
    for (int oi=0;oi<4;++oi){
      const int oc = o0 + wo*64 + oi*16 + lr;
      const float bi = bias[oc];
      #pragma unroll
      for (int i=0;i<4;++i){
        const int nn = n0 + wn*64 + ni*16 + lg*4 + i;
        float v = acc[ni][oi][i] + bi;
        if constexpr (RELU) v = fmaxf(v, 0.f);
        OUT[(long)b*NPT*ors + (long)nn*ors + oc] = (f16)v;
      }
    }
}

// ---------------------------------------------------------------------------
// mlp3 layer1 with fused max, 128x128 tile. grid (16, 8, B). K=512.
// ---------------------------------------------------------------------------
__global__ __launch_bounds__(256, 4) void k_gemmax128(
    const f16* __restrict__ W, const float* __restrict__ bias,
    const f16* __restrict__ XT, float* __restrict__ part)
{
  __shared__ __align__(16) f16 Xs[128][72];
  __shared__ __align__(16) f16 Wsh[128][72];
  __shared__ float red[2][128];
  const int b  = blockIdx.z;
  const int n0 = blockIdx.x * 128;
  const int o0 = blockIdx.y * 128;
  const int tid = threadIdx.x, lane = tid & 63, w = tid >> 6;
  const int lr = lane & 15, lg = lane >> 4;
  const int wn = w >> 1, wo = w & 1;
  const f16* Xb = XT + (long)b*NPT*512;
  f32x4 acc[4][4];
  #pragma unroll
  for (int ni=0;ni<4;++ni)
    #pragma unroll
    for (int oi=0;oi<4;++oi) acc[ni][oi] = (f32x4){0,0,0,0};

  for (int k0=0; k0<512; k0+=64){
    #pragma unroll
    for (int g = tid; g < 1024; g += 256){
      int r = g>>3, s = g&7;
      *(float4*)&Xs[r][s*8]  = *(const float4*)(Xb + (long)(n0+r)*512 + k0 + s*8);
      *(float4*)&Wsh[r][s*8] = *(const float4*)(W + (long)(o0+r)*512 + k0 + s*8);
    }
    __syncthreads();
    #pragma unroll
    for (int ks=0; ks<2; ++ks){
      f16x8 a[4], bf[4];
      #pragma unroll
      for (int ni=0;ni<4;++ni) a[ni]  = *(const f16x8*)&Xs[wn*64 + ni*16 + lr][ks*32 + lg*8];
      #pragma unroll
      for (int oi=0;oi<4;++oi) bf[oi] = *(const f16x8*)&Wsh[wo*64 + oi*16 + lr][ks*32 + lg*8];
      #pragma unroll
      for (int ni=0;ni<4;++ni)
        #pragma unroll
        for (int oi=0;oi<4;++oi) acc[ni][oi] = mfma16(a[ni], bf[oi], acc[ni][oi]);
    }
    __syncthreads();
  }
  #pragma unroll
  for (int oi=0;oi<4;++oi){
    const int oc128 = wo*64 + oi*16 + lr;
    const float bi = bias[o0 + oc128];
    float mv = -1e30f;
    #pragma unroll
    for (int ni=0;ni<4;++ni)
      #pragma unroll
      for (int i=0;i<4;++i) mv = fmaxf(mv, acc[ni][oi][i] + bi);
    mv = fmaxf(mv, __shfl_xor(mv, 16, 64));
    mv = fmaxf(mv, __shfl_xor(mv, 32, 64));
    if (lg == 0) red[wn][oc128] = mv;
  }
  __syncthreads();
  if (tid < 128)
    part[((long)b*1024 + o0 + tid)*16 + blockIdx.x] = fmaxf(red[0][tid], red[1][tid]);
}

// ---------------------------------------------------------------------------
// FUSED v+q GEMM: x = prev + lfT computed in staging.
// ---------------------------------------------------------------------------
__global__ __launch_bounds__(256) void k_vqgemmF(
    const f16* __restrict__ Wv, const float* __restrict__ bv,
    const f16* __restrict__ Wq,
    const f16* __restrict__ prev, int prs,
    const f16* __restrict__ lfT,
    f16* __restrict__ v16, f16* __restrict__ xT, f16* __restrict__ qT)
{
  __shared__ __align__(16) f16 Xs[64][72];
  __shared__ __align__(16) f16 Wsh[64][72];
  const int b  = blockIdx.z;
  const int n0 = blockIdx.x * 64;
  const int c0 = blockIdx.y * 64;
  const int tid = threadIdx.x, lane = tid & 63, w = tid >> 6;
  const int lr = lane & 15, lg = lane >> 4;
  const int wc = w>>1, wn = w&1;
  f32x4 acc[2][2];
  #pragma unroll
  for (int ci=0;ci<2;++ci){ acc[ci][0]=(f32x4){0,0,0,0}; acc[ci][1]=(f32x4){0,0,0,0}; }
  f32x4 accq[2];
  accq[0] = (f32x4){0,0,0,0}; accq[1] = (f32x4){0,0,0,0};

  for (int k0=0; k0<128; k0+=64){
    #pragma unroll
    for (int g = tid; g < 512; g += 256){
      int r = g>>3, s = g&7;
      const long bn = (long)b*NPT + n0 + r;
      f16x8 xa = *(const f16x8*)(prev + bn*prs + k0 + s*8);
      f16x8 l  = *(const f16x8*)(lfT + bn*128 + k0 + s*8);
      f16x8 xv = xa + l;
      *(f16x8*)&Xs[r][s*8] = xv;
      if (c0 != 0) *(f16x8*)(xT + bn*128 + k0 + s*8) = xv;   // x for safin (balanced half)
      *(float4*)&Wsh[r][s*8] = *(const float4*)(Wv + (long)(c0+r)*128 + k0 + s*8);
    }
    __syncthreads();
    #pragma unroll
    for (int ks=0; ks<2; ++ks){
      f16x8 a[2], bf[2];
      #pragma unroll
      for (int ci=0;ci<2;++ci) a[ci] = *(const f16x8*)&Wsh[wc*32 + ci*16 + lr][ks*32 + lg*8];
      #pragma unroll
      for (int ni=0;ni<2;++ni) bf[ni] = *(const f16x8*)&Xs[wn*32 + ni*16 + lr][ks*32 + lg*8];
      #pragma unroll
      for (int ci=0;ci<2;++ci)
        #pragma unroll
        for (int ni=0;ni<2;++ni) acc[ci][ni] = mfma16(a[ci], bf[ni], acc[ci][ni]);
    }
    if (c0 == 0){
      #pragma unroll
      for (int ks=0; ks<2; ++ks){
        f16x8 aq = *(const f16x8*)&Xs[w*16 + lr][ks*32 + lg*8];
        #pragma unroll
        for (int oi=0;oi<2;++oi){
          f16x8 bq = *(const f16x8*)(Wq + (long)(oi*16 + lr)*128 + k0 + ks*32 + lg*8);
          accq[oi] = mfma16(aq, bq, accq[oi]);
        }
      }
    }
    __syncthreads();
  }
  #pragma unroll
  for (int ci=0;ci<2;++ci)
    #pragma unroll
    for (int i=0;i<4;++i){
      const int c = c0 + wc*32 + ci*16 + lg*4 + i;
      const float bi = bv[c];
      #pragma unroll
      for (int ni=0;ni<2;++ni){
        const int n = n0 + wn*32 + ni*16 + lr;
        v16[(long)b*128*NPT + (long)c*NPT + n] = (f16)(acc[ci][ni][i] + bi);
      }
    }
  if (c0 == 0){
    #pragma unroll
    for (int oi=0;oi<2;++oi){
      const int oc = oi*16 + lr;
      #pragma unroll
      for (int i=0;i<4;++i){
        const int nn = n0 + w*16 + lg*4 + i;
        qT[((long)b*NPT + nn)*32 + oc] = (f16)accq[oi][i];
      }
    }
  }
}

// ---------------------------------------------------------------------------
// rowstats PARTIAL (m-split 4-way). grid (32, NRS, B) = 2048 blocks.
// ---------------------------------------------------------------------------
__global__ __launch_bounds__(256) void k_rowstats2(const f16* __restrict__ qT,
                                                   float* __restrict__ mxpart,
                                                   float* __restrict__ smpart)
{
  const int b = blockIdx.z, my = blockIdx.y, n0 = blockIdx.x*64;
  const int tid = threadIdx.x, lane = tid & 63, w = tid >> 6;
  const int lr = lane & 15, lg = lane >> 4;
  const f16* qb = qT + (long)b*NPT*32;
  const f16x8 bfr = *(const f16x8*)(qb + (long)(n0 + w*16 + lr)*32 + lg*8);
  float mx = -1e30f, sm = 0.f;
  const int mBeg = my*(NPT/NRS), mEnd = mBeg + NPT/NRS;
  for (int m0=mBeg; m0<mEnd; m0+=32){
    f16x8 af0 = *(const f16x8*)(qb + (long)(m0+lr)*32 + lg*8);
    f16x8 af1 = *(const f16x8*)(qb + (long)(m0+16+lr)*32 + lg*8);
    f32x4 e0 = mfma16(af0, bfr, (f32x4){0,0,0,0});
    f32x4 e1 = mfma16(af1, bfr, (f32x4){0,0,0,0});
    float t0 = fmaxf(fmaxf(e0[0],e0[1]), fmaxf(e0[2],e0[3]));
    float t1 = fmaxf(fmaxf(e1[0],e1[1]), fmaxf(e1[2],e1[3]));
    float nm = fmaxf(mx, fmaxf(t0, t1));
    sm *= __expf(mx - nm);
    mx = nm;
    sm += __expf(e0[0]-mx) + __expf(e0[1]-mx) + __expf(e0[2]-mx) + __expf(e0[3]-mx)
        + __expf(e1[0]-mx) + __expf(e1[1]-mx) + __expf(e1[2]-mx) + __expf(e1[3]-mx);
  }
  #pragma unroll
  for (int d=16; d<64; d<<=1){
    float omx = __shfl_xor(mx, d, 64);
    float osm = __shfl_xor(sm, d, 64);
    float nm = fmaxf(mx, omx);
    sm = sm*__expf(mx-nm) + osm*__expf(omx-nm);
    mx = nm;
  }
  if (lane < 16){
    const long row = (long)(b*NRS + my);
    mxpart[row*NPT + n0 + w*16 + lr] = mx;
    smpart[row*NPT + n0 + w*16 + lr] = sm;
  }
}

// ---------------------------------------------------------------------------
// fold NRS rowstats partials -> ralpha[b][n] = gm + log(gs). 32768 threads.
// ---------------------------------------------------------------------------
__global__ __launch_bounds__(256) void k_rsfold(const float* __restrict__ mxpart,
                                                const float* __restrict__ smpart,
                                                float* __restrict__ ralpha)
{
  const long idx = (long)blockIdx.x*256 + threadIdx.x;  // 0..B*NPT-1
  const long b = idx >> 11, n = idx & 2047;
  const long r0 = (b*NRS)*NPT + n;
  float gm = mxpart[r0];
  #pragma unroll
  for (int s=1;s<NRS;++s) gm = fmaxf(gm, mxpart[r0 + (long)s*NPT]);
  float gs = 0.f;
  #pragma unroll
  for (int s=0;s<NRS;++s) gs += smpart[r0 + (long)s*NPT] * __expf(mxpart[r0 + (long)s*NPT] - gm);
  ralpha[idx] = gm + __logf(gs);
}

// ---------------------------------------------------------------------------
// pass2 PARTIAL (r23): LDS ps round-trip replaced by round-6-verified
// in-register E^T -> P^T shuffle transpose. vs double-buffer + 1 barrier/tile
// unchanged. NSEG=2. grid (32, NSEG, B).
//   E^T: A = q rows n, B = bfm (wave-private m cols);
//   D: col m (lr), rows n (lg*4+i). exp with folded stats; pack half2;
//   8 shfl + selects rebuild PV A-frag ap[j] = p[nt+lg*8+j][m0w+lr].
// ---------------------------------------------------------------------------
__global__ __launch_bounds__(256) void k_pass2p(const f16* __restrict__ qT,
                                                const f16* __restrict__ v16,
                                                const float* __restrict__ ralpha,
                                                f16* __restrict__ xrpart,
                                                float* __restrict__ cspart)
{
  __shared__ __align__(16) f16 vs[2][128][40];  // double-buffered v-tile [c][n-tile]
  const int b = blockIdx.z, seg = blockIdx.y, m0 = blockIdx.x*64;
  const int tid = threadIdx.x, lane = tid & 63, w = tid >> 6;
  const int lr = lane & 15, lg = lane >> 4;
  const int m0w = m0 + w*16;                    // wave's private 16-m strip
  const f16* qb = qT + (long)b*NPT*32;
  const f16* vb = v16 + (long)b*128*NPT;
  const float* ral = ralpha + (long)b*NPT;
  // E^T B-frag: cols m (wave-private, loop-invariant)
  const f16x8 bfm = *(const f16x8*)(qb + (long)(m0w + lr)*32 + lg*8);
  // shuffle gather lanes (loop-invariant; round-6-verified map)
  const int lo_lane = lr + ((lg & 1) << 5);
  const int hi_lane = lo_lane + 16;
  const bool useA = (lg < 2);
  f16x8 ones;
  #pragma unroll
  for (int j=0;j<8;++j) ones[j] = (f16)1.0f;
  f32x4 acc[8];
  #pragma unroll
  for (int cg=0; cg<8; ++cg) acc[cg] = (f32x4){0,0,0,0};
  f32x4 acc_cs = (f32x4){0,0,0,0};

  const int ntBeg = seg*(NPT/NSEG), ntEnd = ntBeg + NPT/NSEG;
  // prologue: stage first tile into vs[0]
  #pragma unroll
  for (int g = tid; g < 512; g += 256){
    int c = g>>2, s = g&3;
    *(float4*)&vs[0][c][s*8] = *(const float4*)(vb + (long)c*NPT + ntBeg + s*8);
  }
  __syncthreads();
  int cur = 0;

  for (int nt=ntBeg; nt<ntEnd; nt+=32){
    // issue next tile's staging into vs[cur^1] (loads fly under E+PV compute)
    if (nt + 32 < ntEnd){
      #pragma unroll
      for (int g = tid; g < 512; g += 256){
        int c = g>>2, s = g&3;
        *(float4*)&vs[cur^1][c][s*8] = *(const float4*)(vb + (long)c*NPT + nt + 32 + s*8);
      }
    }
    // E^T: two 16x16 tiles covering n in [nt, nt+32)
    f16x8 aA = *(const f16x8*)(qb + (long)(nt + lr)*32 + lg*8);
    f16x8 aB = *(const f16x8*)(qb + (long)(nt + 16 + lr)*32 + lg*8);
    f32x4 eA = mfma16(aA, bfm, (f32x4){0,0,0,0});
    f32x4 eB = mfma16(aB, bfm, (f32x4){0,0,0,0});
    float pA[4], pB[4];
    #pragma unroll
    for (int i=0;i<4;++i){
      pA[i] = __expf(eA[i] - ral[nt + lg*4 + i]);
      pB[i] = __expf(eB[i] - ral[nt + 16 + lg*4 + i]);
    }
    unsigned a01 = pk2(pA[0],pA[1]), a23 = pk2(pA[2],pA[3]);
    unsigned b01 = pk2(pB[0],pB[1]), b23 = pk2(pB[2],pB[3]);
    unsigned w0A = __shfl((int)a01, lo_lane), w0B = __shfl((int)b01, lo_lane);
    unsigned w1A = __shfl((int)a23, lo_lane), w1B = __shfl((int)b23, lo_lane);
    unsigned w2A = __shfl((int)a01, hi_lane), w2B = __shfl((int)b01, hi_lane);
    unsigned w3A = __shfl((int)a23, hi_lane), w3B = __shfl((int)b23, hi_lane);
    union { uint4 u; f16x8 h; } apu;
    apu.u.x = useA ? w0A : w0B;
    apu.u.y = useA ? w1A : w1B;
    apu.u.z = useA ? w2A : w2B;
    apu.u.w = useA ? w3A : w3B;
    const f16x8 ap = apu.h;
    // PV: A = P^T rows m (in-register), B = current v-tile
    #pragma unroll
    for (int cg=0; cg<8; ++cg){
      f16x8 bp = *(const f16x8*)&vs[cur][cg*16 + lr][lg*8];
      acc[cg] = mfma16(ap, bp, acc[cg]);
    }
    acc_cs = mfma16(ap, ones, acc_cs);   // colsum on matrix pipe
    __syncthreads();                      // drains staging; protects vs[cur] reuse
    cur ^= 1;
  }
  const long row = (long)(b*NSEG + seg);
  // acc_cs[i] = cs[m0w + lg*4 + i], duplicated across lr
  if (lr == 0){
    #pragma unroll
    for (int i=0;i<4;++i)
      cspart[row*NPT + m0w + lg*4 + i] = acc_cs[i];
  }
  // raw partial store (no renorm)
  f16* xb = xrpart + row*NPT*128;
  #pragma unroll
  for (int cg=0; cg<8; ++cg)
    #pragma unroll
    for (int i=0;i<4;++i)
      xb[(long)(m0w + lg*4 + i)*128 + cg*16 + lr] = (f16)acc[cg][i];
}

// ---------------------------------------------------------------------------
// gmax over n per (b,c): widened grid (B*8) blocks of 1024.
// ---------------------------------------------------------------------------
__global__ __launch_bounds__(1024) void k_gmaxT(const f16* __restrict__ lfT,
                                                float* __restrict__ gmax8)
{
  __shared__ float red[8][128];
  const int b = blockIdx.x >> 3, h = blockIdx.x & 7;
  const int c = threadIdx.x & 127, r = threadIdx.x >> 7;   // r: 0..7
  const f16* p = lfT + (long)b*NPT*128;
  float m = -1e30f;
  for (int n = h*256 + r; n < (h+1)*256; n += 8) m = fmaxf(m, (float)p[(long)n*128 + c]);
  red[r][c] = m; __syncthreads();
  if (threadIdx.x < 128){
    float mm = red[0][c];
    #pragma unroll
    for (int j=1;j<8;++j) mm = fmaxf(mm, red[j][c]);
    gmax8[((long)b*8 + h)*128 + c] = mm;
  }
}

// gc[b][o] = b0[o] + sum_c w0[o][128+c]*gmax[b][c]; gmax folded from 8 partials
__global__ __launch_bounds__(128) void k_gvec(const float* __restrict__ w0,
                                              const float* __restrict__ b0,
                                              const float* __restrict__ gmax8,
                                              float* __restrict__ gc)
{
  const int b = blockIdx.x, o = threadIdx.x;
  __shared__ float g[128];
  float mm = gmax8[((long)b*8 + 0)*128 + o];
  #pragma unroll
  for (int h=1;h<8;++h) mm = fmaxf(mm, gmax8[((long)b*8 + h)*128 + o]);
  g[o] = mm; __syncthreads();
  float acc = b0[o];
  for (int c = 0; c < 128; ++c) acc = fmaf(w0[o*256 + 128 + c], g[c], acc);
  gc[b*128+o] = acc;
}

// ---------------------------------------------------------------------------
// SA epilogue GEMM with FUSED partial merge (NSEG=2).
// ---------------------------------------------------------------------------
__global__ __launch_bounds__(256) void k_safin2(
    const f16* __restrict__ Wt, const float* __restrict__ bt,
    const float* __restrict__ g, const float* __restrict__ be,
    const f16* __restrict__ xT,
    const f16* __restrict__ xrpart, const float* __restrict__ cspart,
    f16* __restrict__ cat, int Lcol)
{
  __shared__ __align__(16) f16 Xs[64][72];
  __shared__ __align__(16) f16 Wsh[64][72];
  const int b  = blockIdx.z;
  const int n0 = blockIdx.x * 64;
  const int o0 = blockIdx.y * 64;
  const int tid = threadIdx.x, lane = tid & 63, w = tid >> 6;
  const int lr = lane & 15, lg = lane >> 4;
  const int wn = w>>1, wo = w&1;
  const f16* xb = xT + (long)b*NPT*128;
  f32x4 acc[2][2];
  #pragma unroll
  for (int ni=0;ni<2;++ni){ acc[ni][0]=(f32x4){0,0,0,0}; acc[ni][1]=(f32x4){0,0,0,0}; }

  for (int k0=0; k0<128; k0+=64){
    #pragma unroll
    for (int gidx = tid; gidx < 512; gidx += 256){
      int r = gidx>>3, s = gidx&7;
      const long nn = n0 + r;
      const long r0 = ((long)b*NSEG + 0)*NPT + nn;
      const long r1 = r0 + NPT;
      const float inv = 1.f/(1e-9f + cspart[r0] + cspart[r1]);
      f16x8 xa = *(const f16x8*)(xb + nn*128 + k0 + s*8);
      f16x8 p0 = *(const f16x8*)(xrpart + r0*128 + k0 + s*8);
      f16x8 p1 = *(const f16x8*)(xrpart + r1*128 + k0 + s*8);
      f16x8 xs;
      #pragma unroll
      for (int j=0;j<8;++j)
        xs[j] = (f16)((float)xa[j] - ((float)p0[j] + (float)p1[j]) * inv);
      *(f16x8*)&Xs[r][s*8] = xs;
      *(float4*)&Wsh[r][s*8] = *(const float4*)(Wt + (long)(o0+r)*128 + k0 + s*8);
    }
    __syncthreads();
    #pragma unroll
    for (int ks=0; ks<2; ++ks){
      f16x8 a[2], bf[2];
      #pragma unroll
      for (int ni=0;ni<2;++ni) a[ni] = *(const f16x8*)&Xs[wn*32 + ni*16 + lr][ks*32 + lg*8];
      #pragma unroll
      for (int oi=0;oi<2;++oi) bf[oi] = *(const f16x8*)&Wsh[wo*32 + oi*16 + lr][ks*32 + lg*8];
      #pragma unroll
      for (int ni=0;ni<2;++ni)
        #pragma unroll
        for (int oi=0;oi<2;++oi) acc[ni][oi] = mfma16(a[ni], bf[oi], acc[ni][oi]);
    }
    __syncthreads();
  }
  const float bnsc = rsqrtf(1.f + 1e-5f);
  #pragma unroll
  for (int ni=0;ni<2;++ni)
    #pragma unroll
    for (int oi=0;oi<2;++oi){
      const int oc = o0 + wo*32 + oi*16 + lr;
      const float bti = bt[oc], gi = g[oc]*bnsc, bei = be[oc];
      #pragma unroll
      for (int i=0;i<4;++i){
        const int nn = n0 + wn*32 + ni*16 + lg*4 + i;
        float t = acc[ni][oi][i] + bti;
        float val = fmaxf(fmaf(gi, t, bei), 0.f);
        float res = (float)xb[(long)nn*128 + oc];
        cat[(long)b*NPT*384 + (long)nn*384 + Lcol + oc] = (f16)(res + val);
      }
    }
}

__global__ __launch_bounds__(256) void k_maxfinal(const float* __restrict__ part,
                                                  float* __restrict__ out)
{
  const int t = blockIdx.x*256 + threadIdx.x;   // 0..16383
  float m = -1e30f;
  #pragma unroll
  for (int j=0;j<16;++j) m = fmaxf(m, part[(long)t*16 + j]);
  out[t] = m;
}

// ---------------------------------------------------------------------------
extern "C" void kernel_launch(void* const* d_in, const int* in_sizes, int n_in,
                              void* d_out, int out_size, void* d_ws, size_t ws_size,
                              hipStream_t stream)
{
  const float* in   = (const float*)d_in[0];
  const float* m1w0 = (const float*)d_in[1];
  const float* m1b0 = (const float*)d_in[2];
  const float* m1w1 = (const float*)d_in[3];
  const float* m1b1 = (const float*)d_in[4];
  const float* m2w0 = (const float*)d_in[5];
  const float* m2b0 = (const float*)d_in[6];
  const float* m2w1 = (const float*)d_in[7];
  const float* m2b1 = (const float*)d_in[8];
  const float* m3w0 = (const float*)d_in[9];
  const float* m3b0 = (const float*)d_in[10];
  const float* m3w1 = (const float*)d_in[11];
  const float* m3b1 = (const float*)d_in[12];

  // ws layout (halfs)
  f16* ws16 = (f16*)d_ws;
  f16* W16  = ws16;                       // 880,640
  f16* lfT  = ws16 + 880640;              // [B][N][128]
  f16* xT   = ws16 + 5074944;             // [B][N][128]
  f16* qT   = ws16 + 9269248;             // [B][N][32]
  f16* vbuf = ws16 + 10317824;            // [B][128][N]
  f16* xrT  = ws16 + 14512128;            // [B][N][128] (mlp2 features)
  f16* hT   = ws16 + 18706432;            // [B][N][512] (mlp3 hidden)
  f16* xrpart = hT;                       // [B*NSEG][N][128] — aliases hT (dead during SA)
  f16* catT = ws16 + 35483648;            // [B][N][384]
  float* fb = (float*)(ws16 + 48066560);
  float* ralpha = fb;                     // [B,N] (folded rmax+log(rsum))
  float* gc     = fb + 67584;             // [B,128]
  float* part   = fb + 69632;             // [B,1024,16]
  float* cspart = fb + 593920;            // [B*NSEG][N]
  float* gmax8  = fb + 659456;            // [B][8][128]
  float* mxpart = fb + 675840;            // [B*NRS][N]
  float* smpart = fb + 806912;            // [B*NRS][N]

  const dim3 blk(256);

  k_wconv<<<dim3((WTOT+255)/256), blk, 0, stream>>>(
      m1w1, m2w0, m2w1, m3w0, m3w1,
      (const float*)d_in[13], (const float*)d_in[14], (const float*)d_in[16],
      (const float*)d_in[20], (const float*)d_in[21], (const float*)d_in[23],
      (const float*)d_in[27], (const float*)d_in[28], (const float*)d_in[30],
      W16);

  // mlp1 (fused l0+l1)
  k_mlp1f<<<dim3(32,NBAT), blk, 0, stream>>>(in, m1w0, m1b0, W16+OFF_M1W1, m1b1, lfT);
  // global max (widened) + mlp2 (fused l0+l1) -> features in xrT
  k_gmaxT<<<dim3(NBAT*8), dim3(1024), 0, stream>>>(lfT, gmax8);
  k_gvec<<<dim3(NBAT), dim3(128), 0, stream>>>(m2w0, m2b0, gmax8, gc);
  k_mlp2f<<<dim3(32,NBAT), blk, 0, stream>>>(
      W16+OFF_M2W0A, gc, W16+OFF_M2W1, m2b1, lfT, xrT);

  // 3 SA layers
  for (int L = 0; L < 3; ++L){
    const float* bv = (const float*)d_in[13 + L*7 + 2];
    const float* bt = (const float*)d_in[13 + L*7 + 4];
    const float* gg = (const float*)d_in[13 + L*7 + 5];
    const float* be = (const float*)d_in[13 + L*7 + 6];
    const f16* wq16 = W16 + OFF_SA + L*SA_STRIDE;
    const f16* wv16 = wq16 + 4096;
    const f16* wt16 = wq16 + 20480;

    const f16* prev = (L==0) ? xrT : (catT + (long)(L-1)*128);
    const int  prs  = (L==0) ? 128 : 384;

    k_vqgemmF<<<dim3(32,2,NBAT), blk, 0, stream>>>(
        wv16, bv, wq16, prev, prs, lfT, vbuf, xT, qT);
    k_rowstats2<<<dim3(32,NRS,NBAT), blk, 0, stream>>>(qT, mxpart, smpart);
    k_rsfold<<<dim3(NBAT*NPT/256), blk, 0, stream>>>(mxpart, smpart, ralpha);
    k_pass2p<<<dim3(32,NSEG,NBAT), blk, 0, stream>>>(qT, vbuf, ralpha, xrpart, cspart);
    k_safin2<<<dim3(32,2,NBAT), blk, 0, stream>>>(
        wt16, bt, gg, be, xT, xrpart, cspart, catT, L*128);
  }

  // mlp3: layer0 (384->512 relu) 128x128 tile, layer1 fused-max 128x128
  gemm128<true><<<dim3(16,4,NBAT), blk, 0, stream>>>(
      W16+OFF_M3W0, m3b0, catT, 384, hT, 512, 384);
  k_gemmax128<<<dim3(16,8,NBAT), blk, 0, stream>>>(W16+OFF_M3W1, m3b1, hT, part);
  k_maxfinal<<<dim3(64), blk, 0, stream>>>(part, (float*)d_out);
}

// Round 24
// 387.000 us; speedup vs baseline: 1.0365x; 1.0365x over previous
//
#include <hip/hip_runtime.h>
#include <hip/hip_bf16.h>
#include <cfloat>

static constexpr int NBAT = 16;
static constexpr int NPT  = 2048;
static constexpr int NSEG = 2;     // pass2 n-split segments
static constexpr int NRS  = 4;     // rowstats m-split segments

typedef _Float16 f16;
typedef _Float16 f16x8 __attribute__((ext_vector_type(8)));
typedef float    f32x4 __attribute__((ext_vector_type(4)));

static __device__ __forceinline__ f32x4 mfma16(f16x8 a, f16x8 b, f32x4 c){
  return __builtin_amdgcn_mfma_f32_16x16x32_f16(a, b, c, 0, 0, 0);
}
// MFMA 16x16x32 f16 layouts (gfx950, e2e-verified by round-4 pass):
//  A[16r x 32k]: lane l -> row l&15, k = (l>>4)*8 + j (16B contiguous)
//  B[32k x 16c]: lane l -> col l&15, k = (l>>4)*8 + j (16B contiguous)
//  D[16r x 16c]: lane l -> col l&15, rows (l>>4)*4 + i

// ---- weight arena offsets (halfs) ----
static constexpr long OFF_M1W1 = 0;              // [128][128]
static constexpr long OFF_M2W0A= 16384;          // [128][128] (cols 0..127 of [128][256])
static constexpr long OFF_M2W1 = 32768;          // [128][128]
static constexpr long OFF_M3W0 = 49152;          // [512][384]
static constexpr long OFF_M3W1 = 245760;         // [1024][512]
static constexpr long OFF_SA   = 770048;         // per-L: wq[32][128], wv[128][128], wt[128][128]
static constexpr long SA_STRIDE= 36864;
static constexpr long WTOT     = OFF_SA + 3*SA_STRIDE;   // 880,640 halfs

// ---------------------------------------------------------------------------
// weight fp32 -> fp16 conversion into arena (one launch)
// ---------------------------------------------------------------------------
__global__ __launch_bounds__(256) void k_wconv(
    const float* m1w1, const float* m2w0, const float* m2w1,
    const float* m3w0, const float* m3w1,
    const float* wq0, const float* wv0, const float* wt0,
    const float* wq1, const float* wv1, const float* wt1,
    const float* wq2, const float* wv2, const float* wt2,
    f16* W)
{
  long t = (long)blockIdx.x*256 + threadIdx.x;
  if (t >= WTOT) return;
  float v;
  if      (t < OFF_M2W0A) v = m1w1[t];
  else if (t < OFF_M2W1) { long u = t-OFF_M2W0A; v = m2w0[(u>>7)*256 + (u&127)]; }
  else if (t < OFF_M3W0)  v = m2w1[t-OFF_M2W1];
  else if (t < OFF_M3W1)  v = m3w0[t-OFF_M3W0];
  else if (t < OFF_SA)    v = m3w1[t-OFF_M3W1];
  else {
    long u = t - OFF_SA; int L = (int)(u / SA_STRIDE); long r = u % SA_STRIDE;
    const float* wq = (L==0)?wq0:(L==1)?wq1:wq2;
    const float* wv = (L==0)?wv0:(L==1)?wv1:wv2;
    const float* wt = (L==0)?wt0:(L==1)?wt1:wt2;
    if (r < 4096) v = wq[r]; else if (r < 20480) v = wv[r-4096]; else v = wt[r-20480];
  }
  W[t] = (f16)v;
}

// ---------------------------------------------------------------------------
// FUSED mlp1: h1 tile computed in LDS (K=3 pointwise), then l1 GEMM.
// ---------------------------------------------------------------------------
__global__ __launch_bounds__(256) void k_mlp1f(
    const float* __restrict__ in, const float* __restrict__ w0,
    const float* __restrict__ b0,
    const f16* __restrict__ W1, const float* __restrict__ b1,
    f16* __restrict__ lfT)
{
  __shared__ __align__(16) f16 Hs[64][136];   // hidden tile, full K=128
  __shared__ __align__(16) f16 Wsh[64][72];
  const int b = blockIdx.y, n0 = blockIdx.x*64;
  const int tid = threadIdx.x, lane = tid & 63, w = tid >> 6;
  const int lr = lane & 15, lg = lane >> 4;
  const int wn = w>>1, wo = w&1;
  for (int e = tid; e < 64*128; e += 256){
    int r = e >> 7, o = e & 127;
    const float* ip = in + ((long)b*NPT + n0 + r)*3;
    float v = b0[o] + w0[o*3]*ip[0] + w0[o*3+1]*ip[1] + w0[o*3+2]*ip[2];
    Hs[r][o] = (f16)fmaxf(v, 0.f);
  }
  __syncthreads();
  f32x4 acc[2][2][2];
  #pragma unroll
  for (int oh=0;oh<2;++oh)
    #pragma unroll
    for (int ni=0;ni<2;++ni)
      #pragma unroll
      for (int oi=0;oi<2;++oi) acc[oh][ni][oi] = (f32x4){0,0,0,0};

  #pragma unroll
  for (int k0=0;k0<128;k0+=64){
    #pragma unroll
    for (int oh=0;oh<2;++oh){
      for (int g=tid; g<512; g+=256){
        int r=g>>3, s=g&7;
        *(float4*)&Wsh[r][s*8] = *(const float4*)(W1 + (long)(oh*64+r)*128 + k0 + s*8);
      }
      __syncthreads();
      #pragma unroll
      for (int ks=0;ks<2;++ks){
        f16x8 a[2], bf[2];
        #pragma unroll
        for (int ni=0;ni<2;++ni) a[ni] = *(const f16x8*)&Hs[wn*32+ni*16+lr][k0+ks*32+lg*8];
        #pragma unroll
        for (int oi=0;oi<2;++oi) bf[oi] = *(const f16x8*)&Wsh[wo*32+oi*16+lr][ks*32+lg*8];
        #pragma unroll
        for (int ni=0;ni<2;++ni)
          #pragma unroll
          for (int oi=0;oi<2;++oi) acc[oh][ni][oi] = mfma16(a[ni], bf[oi], acc[oh][ni][oi]);
      }
      __syncthreads();
    }
  }
  #pragma unroll
  for (int oh=0;oh<2;++oh)
    #pragma unroll
    for (int ni=0;ni<2;++ni)
      #pragma unroll
      for (int oi=0;oi<2;++oi){
        const int oc = oh*64 + wo*32 + oi*16 + lr;
        const float bi = b1[oc];
        #pragma unroll
        for (int i=0;i<4;++i){
          const int nn = n0 + wn*32 + ni*16 + lg*4 + i;
          lfT[((long)b*NPT + nn)*128 + oc] = (f16)(acc[oh][ni][oi][i] + bi);
        }
      }
}

// ---------------------------------------------------------------------------
// FUSED mlp2: GEMM0 (lfT -> h, relu, gc bias) into LDS, then GEMM1.
// ---------------------------------------------------------------------------
__global__ __launch_bounds__(256) void k_mlp2f(
    const f16* __restrict__ W0, const float* __restrict__ gc,
    const f16* __restrict__ W1, const float* __restrict__ b1,
    const f16* __restrict__ lfT, f16* __restrict__ featT)
{
  __shared__ __align__(16) f16 Xs[64][72];
  __shared__ __align__(16) f16 Hs[64][136];
  __shared__ __align__(16) f16 Wsh[64][72];
  const int b = blockIdx.y, n0 = blockIdx.x*64;
  const int tid = threadIdx.x, lane = tid & 63, w = tid >> 6;
  const int lr = lane & 15, lg = lane >> 4;
  const int wn = w>>1, wo = w&1;
  const f16* Xb = lfT + (long)b*NPT*128;
  f32x4 acc[2][2][2];
  #pragma unroll
  for (int oh=0;oh<2;++oh)
    #pragma unroll
    for (int ni=0;ni<2;++ni)
      #pragma unroll
      for (int oi=0;oi<2;++oi) acc[oh][ni][oi] = (f32x4){0,0,0,0};

  #pragma unroll
  for (int k0=0;k0<128;k0+=64){
    for (int g=tid; g<512; g+=256){
      int r=g>>3, s=g&7;
      *(float4*)&Xs[r][s*8] = *(const float4*)(Xb + (long)(n0+r)*128 + k0 + s*8);
    }
    #pragma unroll
    for (int oh=0;oh<2;++oh){
      for (int g=tid; g<512; g+=256){
        int r=g>>3, s=g&7;
        *(float4*)&Wsh[r][s*8] = *(const float4*)(W0 + (long)(oh*64+r)*128 + k0 + s*8);
      }
      __syncthreads();
      #pragma unroll
      for (int ks=0;ks<2;++ks){
        f16x8 a[2], bf[2];
        #pragma unroll
        for (int ni=0;ni<2;++ni) a[ni] = *(const f16x8*)&Xs[wn*32+ni*16+lr][ks*32+lg*8];
        #pragma unroll
        for (int oi=0;oi<2;++oi) bf[oi] = *(const f16x8*)&Wsh[wo*32+oi*16+lr][ks*32+lg*8];
        #pragma unroll
        for (int ni=0;ni<2;++ni)
          #pragma unroll
          for (int oi=0;oi<2;++oi) acc[oh][ni][oi] = mfma16(a[ni], bf[oi], acc[oh][ni][oi]);
      }
      __syncthreads();
    }
  }
  #pragma unroll
  for (int oh=0;oh<2;++oh)
    #pragma unroll
    for (int ni=0;ni<2;++ni)
      #pragma unroll
      for (int oi=0;oi<2;++oi){
        const int oc = oh*64 + wo*32 + oi*16 + lr;
        const float bi = gc[b*128 + oc];
        #pragma unroll
        for (int i=0;i<4;++i){
          const int rl = wn*32 + ni*16 + lg*4 + i;
          Hs[rl][oc] = (f16)fmaxf(acc[oh][ni][oi][i] + bi, 0.f);
        }
      }
  __syncthreads();

  #pragma unroll
  for (int oh=0;oh<2;++oh)
    #pragma unroll
    for (int ni=0;ni<2;++ni)
      #pragma unroll
      for (int oi=0;oi<2;++oi) acc[oh][ni][oi] = (f32x4){0,0,0,0};
  #pragma unroll
  for (int k0=0;k0<128;k0+=64){
    #pragma unroll
    for (int oh=0;oh<2;++oh){
      for (int g=tid; g<512; g+=256){
        int r=g>>3, s=g&7;
        *(float4*)&Wsh[r][s*8] = *(const float4*)(W1 + (long)(oh*64+r)*128 + k0 + s*8);
      }
      __syncthreads();
      #pragma unroll
      for (int ks=0;ks<2;++ks){
        f16x8 a[2], bf[2];
        #pragma unroll
        for (int ni=0;ni<2;++ni) a[ni] = *(const f16x8*)&Hs[wn*32+ni*16+lr][k0+ks*32+lg*8];
        #pragma unroll
        for (int oi=0;oi<2;++oi) bf[oi] = *(const f16x8*)&Wsh[wo*32+oi*16+lr][ks*32+lg*8];
        #pragma unroll
        for (int ni=0;ni<2;++ni)
          #pragma unroll
          for (int oi=0;oi<2;++oi) acc[oh][ni][oi] = mfma16(a[ni], bf[oi], acc[oh][ni][oi]);
      }
      __syncthreads();
    }
  }
  #pragma unroll
  for (int oh=0;oh<2;++oh)
    #pragma unroll
    for (int ni=0;ni<2;++ni)
      #pragma unroll
      for (int oi=0;oi<2;++oi){
        const int oc = oh*64 + wo*32 + oi*16 + lr;
        const float bi = b1[oc];
        #pragma unroll
        for (int i=0;i<4;++i){
          const int nn = n0 + wn*32 + ni*16 + lg*4 + i;
          featT[((long)b*NPT + nn)*128 + oc] = (f16)(acc[oh][ni][oi][i] + bi);
        }
      }
}

// ---------------------------------------------------------------------------
// 128x128-tile GEMM (4 waves as 2x2, each wave 64x64, acc[4][4]).
// ---------------------------------------------------------------------------
template<bool RELU>
__global__ __launch_bounds__(256, 4) void gemm128(
    const f16* __restrict__ W, const float* __restrict__ bias,
    const f16* __restrict__ XT, int xrs,
    f16* __restrict__ OUT, int ors, int K)
{
  __shared__ __align__(16) f16 Xs[128][72];
  __shared__ __align__(16) f16 Wsh[128][72];
  const int b  = blockIdx.z;
  const int n0 = blockIdx.x * 128;
  const int o0 = blockIdx.y * 128;
  const int tid = threadIdx.x, lane = tid & 63, w = tid >> 6;
  const int lr = lane & 15, lg = lane >> 4;
  const int wn = w >> 1, wo = w & 1;
  const f16* Xb = XT + (long)b*NPT*xrs;
  f32x4 acc[4][4];
  #pragma unroll
  for (int ni=0;ni<4;++ni)
    #pragma unroll
    for (int oi=0;oi<4;++oi) acc[ni][oi] = (f32x4){0,0,0,0};

  for (int k0=0; k0<K; k0+=64){
    #pragma unroll
    for (int g = tid; g < 1024; g += 256){
      int r = g>>3, s = g&7;
      *(float4*)&Xs[r][s*8]  = *(const float4*)(Xb + (long)(n0+r)*xrs + k0 + s*8);
      *(float4*)&Wsh[r][s*8] = *(const float4*)(W + (long)(o0+r)*K + k0 + s*8);
    }
    __syncthreads();
    #pragma unroll
    for (int ks=0; ks<2; ++ks){
      f16x8 a[4], bf[4];
      #pragma unroll
      for (int ni=0;ni<4;++ni) a[ni]  = *(const f16x8*)&Xs[wn*64 + ni*16 + lr][ks*32 + lg*8];
      #pragma unroll
      for (int oi=0;oi<4;++oi) bf[oi] = *(const f16x8*)&Wsh[wo*64 + oi*16 + lr][ks*32 + lg*8];
      #pragma unroll
      for (int ni=0;ni<4;++ni)
        #pragma unroll
        for (int oi=0;oi<4;++oi) acc[ni][oi] = mfma16(a[ni], bf[oi], acc[ni][oi]);
    }
    __syncthreads();
  }
  #pragma unroll
  for (int ni=0;ni<4;++ni)
    #pragma unroll
    for (int oi=0;oi<4;++oi){
      const int oc = o0 + wo*64 + oi*16 + lr;
      const float bi = bias[oc];
      #pragma unroll
      for (int i=0;i<4;++i){
        const int nn = n0 + wn*64 + ni*16 + lg*4 + i;
        float v = acc[ni][oi][i] + bi;
        if constexpr (RELU) v = fmaxf(v, 0.f);
        OUT[(long)b*NPT*ors + (long)nn*ors + oc] = (f16)v;
      }
    }
}

// ---------------------------------------------------------------------------
// mlp3 layer1 with fused max, 128x128 tile. grid (16, 8, B). K=512.
// ---------------------------------------------------------------------------
__global__ __launch_bounds__(256, 4) void k_gemmax128(
    const f16* __restrict__ W, const float* __restrict__ bias,
    const f16* __restrict__ XT, float* __restrict__ part)
{
  __shared__ __align__(16) f16 Xs[128][72];
  __shared__ __align__(16) f16 Wsh[128][72];
  __shared__ float red[2][128];
  const int b  = blockIdx.z;
  const int n0 = blockIdx.x * 128;
  const int o0 = blockIdx.y * 128;
  const int tid = threadIdx.x, lane = tid & 63, w = tid >> 6;
  const int lr = lane & 15, lg = lane >> 4;
  const int wn = w >> 1, wo = w & 1;
  const f16* Xb = XT + (long)b*NPT*512;
  f32x4 acc[4][4];
  #pragma unroll
  for (int ni=0;ni<4;++ni)
    #pragma unroll
    for (int oi=0;oi<4;++oi) acc[ni][oi] = (f32x4){0,0,0,0};

  for (int k0=0; k0<512; k0+=64){
    #pragma unroll
    for (int g = tid; g < 1024; g += 256){
      int r = g>>3, s = g&7;
      *(float4*)&Xs[r][s*8]  = *(const float4*)(Xb + (long)(n0+r)*512 + k0 + s*8);
      *(float4*)&Wsh[r][s*8] = *(const float4*)(W + (long)(o0+r)*512 + k0 + s*8);
    }
    __syncthreads();
    #pragma unroll
    for (int ks=0; ks<2; ++ks){
      f16x8 a[4], bf[4];
      #pragma unroll
      for (int ni=0;ni<4;++ni) a[ni]  = *(const f16x8*)&Xs[wn*64 + ni*16 + lr][ks*32 + lg*8];
      #pragma unroll
      for (int oi=0;oi<4;++oi) bf[oi] = *(const f16x8*)&Wsh[wo*64 + oi*16 + lr][ks*32 + lg*8];
      #pragma unroll
      for (int ni=0;ni<4;++ni)
        #pragma unroll
        for (int oi=0;oi<4;++oi) acc[ni][oi] = mfma16(a[ni], bf[oi], acc[ni][oi]);
    }
    __syncthreads();
  }
  #pragma unroll
  for (int oi=0;oi<4;++oi){
    const int oc128 = wo*64 + oi*16 + lr;
    const float bi = bias[o0 + oc128];
    float mv = -1e30f;
    #pragma unroll
    for (int ni=0;ni<4;++ni)
      #pragma unroll
      for (int i=0;i<4;++i) mv = fmaxf(mv, acc[ni][oi][i] + bi);
    mv = fmaxf(mv, __shfl_xor(mv, 16, 64));
    mv = fmaxf(mv, __shfl_xor(mv, 32, 64));
    if (lg == 0) red[wn][oc128] = mv;
  }
  __syncthreads();
  if (tid < 128)
    part[((long)b*1024 + o0 + tid)*16 + blockIdx.x] = fmaxf(red[0][tid], red[1][tid]);
}

// ---------------------------------------------------------------------------
// FUSED v+q GEMM: x = prev + lfT computed in staging.
// v16[b][c][n] for all blocks; c0==0 blocks compute qT (o<32, Wq direct from
// global); c0!=0 blocks write staged x to xT. grid (32, 2, B).
// ---------------------------------------------------------------------------
__global__ __launch_bounds__(256) void k_vqgemmF(
    const f16* __restrict__ Wv, const float* __restrict__ bv,
    const f16* __restrict__ Wq,
    const f16* __restrict__ prev, int prs,
    const f16* __restrict__ lfT,
    f16* __restrict__ v16, f16* __restrict__ xT, f16* __restrict__ qT)
{
  __shared__ __align__(16) f16 Xs[64][72];
  __shared__ __align__(16) f16 Wsh[64][72];
  const int b  = blockIdx.z;
  const int n0 = blockIdx.x * 64;
  const int c0 = blockIdx.y * 64;
  const int tid = threadIdx.x, lane = tid & 63, w = tid >> 6;
  const int lr = lane & 15, lg = lane >> 4;
  const int wc = w>>1, wn = w&1;
  f32x4 acc[2][2];
  #pragma unroll
  for (int ci=0;ci<2;++ci){ acc[ci][0]=(f32x4){0,0,0,0}; acc[ci][1]=(f32x4){0,0,0,0}; }
  f32x4 accq[2];
  accq[0] = (f32x4){0,0,0,0}; accq[1] = (f32x4){0,0,0,0};

  for (int k0=0; k0<128; k0+=64){
    #pragma unroll
    for (int g = tid; g < 512; g += 256){
      int r = g>>3, s = g&7;
      const long bn = (long)b*NPT + n0 + r;
      f16x8 xa = *(const f16x8*)(prev + bn*prs + k0 + s*8);
      f16x8 l  = *(const f16x8*)(lfT + bn*128 + k0 + s*8);
      f16x8 xv = xa + l;
      *(f16x8*)&Xs[r][s*8] = xv;
      if (c0 != 0) *(f16x8*)(xT + bn*128 + k0 + s*8) = xv;   // x for safin (balanced half)
      *(float4*)&Wsh[r][s*8] = *(const float4*)(Wv + (long)(c0+r)*128 + k0 + s*8);
    }
    __syncthreads();
    #pragma unroll
    for (int ks=0; ks<2; ++ks){
      f16x8 a[2], bf[2];
      #pragma unroll
      for (int ci=0;ci<2;++ci) a[ci] = *(const f16x8*)&Wsh[wc*32 + ci*16 + lr][ks*32 + lg*8];
      #pragma unroll
      for (int ni=0;ni<2;++ni) bf[ni] = *(const f16x8*)&Xs[wn*32 + ni*16 + lr][ks*32 + lg*8];
      #pragma unroll
      for (int ci=0;ci<2;++ci)
        #pragma unroll
        for (int ni=0;ni<2;++ni) acc[ci][ni] = mfma16(a[ci], bf[ni], acc[ci][ni]);
    }
    if (c0 == 0){
      // q: A = Xs rows n (wave w owns n0+w*16..+15), B = Wq direct from global
      #pragma unroll
      for (int ks=0; ks<2; ++ks){
        f16x8 aq = *(const f16x8*)&Xs[w*16 + lr][ks*32 + lg*8];
        #pragma unroll
        for (int oi=0;oi<2;++oi){
          f16x8 bq = *(const f16x8*)(Wq + (long)(oi*16 + lr)*128 + k0 + ks*32 + lg*8);
          accq[oi] = mfma16(aq, bq, accq[oi]);
        }
      }
    }
    __syncthreads();
  }
  #pragma unroll
  for (int ci=0;ci<2;++ci)
    #pragma unroll
    for (int i=0;i<4;++i){
      const int c = c0 + wc*32 + ci*16 + lg*4 + i;
      const float bi = bv[c];
      #pragma unroll
      for (int ni=0;ni<2;++ni){
        const int n = n0 + wn*32 + ni*16 + lr;
        v16[(long)b*128*NPT + (long)c*NPT + n] = (f16)(acc[ci][ni][i] + bi);
      }
    }
  if (c0 == 0){
    #pragma unroll
    for (int oi=0;oi<2;++oi){
      const int oc = oi*16 + lr;
      #pragma unroll
      for (int i=0;i<4;++i){
        const int nn = n0 + w*16 + lg*4 + i;
        qT[((long)b*NPT + nn)*32 + oc] = (f16)accq[oi][i];
      }
    }
  }
}

// ---------------------------------------------------------------------------
// rowstats PARTIAL (m-split 4-way). grid (32, NRS, B) = 2048 blocks.
// ---------------------------------------------------------------------------
__global__ __launch_bounds__(256) void k_rowstats2(const f16* __restrict__ qT,
                                                   float* __restrict__ mxpart,
                                                   float* __restrict__ smpart)
{
  const int b = blockIdx.z, my = blockIdx.y, n0 = blockIdx.x*64;
  const int tid = threadIdx.x, lane = tid & 63, w = tid >> 6;
  const int lr = lane & 15, lg = lane >> 4;
  const f16* qb = qT + (long)b*NPT*32;
  const f16x8 bfr = *(const f16x8*)(qb + (long)(n0 + w*16 + lr)*32 + lg*8);
  float mx = -1e30f, sm = 0.f;
  const int mBeg = my*(NPT/NRS), mEnd = mBeg + NPT/NRS;
  for (int m0=mBeg; m0<mEnd; m0+=32){
    f16x8 af0 = *(const f16x8*)(qb + (long)(m0+lr)*32 + lg*8);
    f16x8 af1 = *(const f16x8*)(qb + (long)(m0+16+lr)*32 + lg*8);
    f32x4 e0 = mfma16(af0, bfr, (f32x4){0,0,0,0});
    f32x4 e1 = mfma16(af1, bfr, (f32x4){0,0,0,0});
    float t0 = fmaxf(fmaxf(e0[0],e0[1]), fmaxf(e0[2],e0[3]));
    float t1 = fmaxf(fmaxf(e1[0],e1[1]), fmaxf(e1[2],e1[3]));
    float nm = fmaxf(mx, fmaxf(t0, t1));
    sm *= __expf(mx - nm);
    mx = nm;
    sm += __expf(e0[0]-mx) + __expf(e0[1]-mx) + __expf(e0[2]-mx) + __expf(e0[3]-mx)
        + __expf(e1[0]-mx) + __expf(e1[1]-mx) + __expf(e1[2]-mx) + __expf(e1[3]-mx);
  }
  #pragma unroll
  for (int d=16; d<64; d<<=1){
    float omx = __shfl_xor(mx, d, 64);
    float osm = __shfl_xor(sm, d, 64);
    float nm = fmaxf(mx, omx);
    sm = sm*__expf(mx-nm) + osm*__expf(omx-nm);
    mx = nm;
  }
  if (lane < 16){
    const long row = (long)(b*NRS + my);
    mxpart[row*NPT + n0 + w*16 + lr] = mx;
    smpart[row*NPT + n0 + w*16 + lr] = sm;
  }
}

// ---------------------------------------------------------------------------
// fold NRS rowstats partials -> ralpha[b][n] = gm + log(gs). 32768 threads.
// ---------------------------------------------------------------------------
__global__ __launch_bounds__(256) void k_rsfold(const float* __restrict__ mxpart,
                                                const float* __restrict__ smpart,
                                                float* __restrict__ ralpha)
{
  const long idx = (long)blockIdx.x*256 + threadIdx.x;  // 0..B*NPT-1
  const long b = idx >> 11, n = idx & 2047;
  const long r0 = (b*NRS)*NPT + n;
  float gm = mxpart[r0];
  #pragma unroll
  for (int s=1;s<NRS;++s) gm = fmaxf(gm, mxpart[r0 + (long)s*NPT]);
  float gs = 0.f;
  #pragma unroll
  for (int s=0;s<NRS;++s) gs += smpart[r0 + (long)s*NPT] * __expf(mxpart[r0 + (long)s*NPT] - gm);
  ralpha[idx] = gm + __logf(gs);
}

// ---------------------------------------------------------------------------
// pass2 PARTIAL [proven kernel: 64-m blocks, 2-deep pipelined V staging,
// one barrier/tile, ones-MFMA colsum, folded stats]. NSEG=2. grid (32,NSEG,B).
// ---------------------------------------------------------------------------
__global__ __launch_bounds__(256) void k_pass2p(const f16* __restrict__ qT,
                                                const f16* __restrict__ v16,
                                                const float* __restrict__ ralpha,
                                                f16* __restrict__ xrpart,
                                                float* __restrict__ cspart)
{
  __shared__ __align__(16) f16 ps[64][40];      // pT[m][n-tile]; rows wave-private
  __shared__ __align__(16) f16 vs[2][128][40];  // double-buffered v-tile [c][n-tile]
  const int b = blockIdx.z, seg = blockIdx.y, m0 = blockIdx.x*64;
  const int tid = threadIdx.x, lane = tid & 63, w = tid >> 6;
  const int lr = lane & 15, lg = lane >> 4;
  const f16* qb = qT + (long)b*NPT*32;
  const f16* vb = v16 + (long)b*128*NPT;
  const float* ral = ralpha + (long)b*NPT;
  const f16x8 afe = *(const f16x8*)(qb + (long)(m0 + w*16 + lr)*32 + lg*8);  // E A-frag (rows m)
  f16x8 ones;
  #pragma unroll
  for (int j=0;j<8;++j) ones[j] = (f16)1.0f;
  f32x4 acc[8];
  #pragma unroll
  for (int cg=0; cg<8; ++cg) acc[cg] = (f32x4){0,0,0,0};
  f32x4 acc_cs = (f32x4){0,0,0,0};

  const int ntBeg = seg*(NPT/NSEG), ntEnd = ntBeg + NPT/NSEG;
  // prologue: stage first tile into vs[0]
  #pragma unroll
  for (int g = tid; g < 512; g += 256){
    int c = g>>2, s = g&3;
    *(float4*)&vs[0][c][s*8] = *(const float4*)(vb + (long)c*NPT + ntBeg + s*8);
  }
  __syncthreads();
  int cur = 0;

  for (int nt=ntBeg; nt<ntEnd; nt+=32){
    // issue next tile's staging into vs[cur^1] (loads fly under E+PV compute)
    if (nt + 32 < ntEnd){
      #pragma unroll
      for (int g = tid; g < 512; g += 256){
        int c = g>>2, s = g&3;
        *(float4*)&vs[cur^1][c][s*8] = *(const float4*)(vb + (long)c*NPT + nt + 32 + s*8);
      }
    }
    // E phase: 2 col-groups; lane col n fixed, 4 m-rows (ps wave-private)
    #pragma unroll
    for (int ng=0; ng<2; ++ng){
      f16x8 bfe = *(const f16x8*)(qb + (long)(nt + ng*16 + lr)*32 + lg*8);
      f32x4 e = mfma16(afe, bfe, (f32x4){0,0,0,0});
      const float ra = ral[nt + ng*16 + lr];
      #pragma unroll
      for (int i=0;i<4;++i){
        float p = __expf(e[i] - ra);
        ps[w*16 + lg*4 + i][ng*16 + lr] = (f16)p;
      }
    }
    // PV phase: A = pT rows m (wave-private), B = current v-tile
    f16x8 ap = *(const f16x8*)&ps[w*16 + lr][lg*8];
    #pragma unroll
    for (int cg=0; cg<8; ++cg){
      f16x8 bp = *(const f16x8*)&vs[cur][cg*16 + lr][lg*8];
      acc[cg] = mfma16(ap, bp, acc[cg]);
    }
    acc_cs = mfma16(ap, ones, acc_cs);   // colsum on matrix pipe
    __syncthreads();                      // drains staging; protects vs[cur] reuse
    cur ^= 1;
  }
  const long row = (long)(b*NSEG + seg);
  // acc_cs[i] = cs[m0 + w*16 + lg*4 + i], duplicated across lr
  if (lr == 0){
    #pragma unroll
    for (int i=0;i<4;++i)
      cspart[row*NPT + m0 + w*16 + lg*4 + i] = acc_cs[i];
  }
  // raw partial store (no renorm)
  f16* xb = xrpart + row*NPT*128;
  #pragma unroll
  for (int cg=0; cg<8; ++cg)
    #pragma unroll
    for (int i=0;i<4;++i)
      xb[(long)(m0 + w*16 + lg*4 + i)*128 + cg*16 + lr] = (f16)acc[cg][i];
}

// ---------------------------------------------------------------------------
// gmax over n per (b,c): widened grid (B*8) blocks of 1024.
// ---------------------------------------------------------------------------
__global__ __launch_bounds__(1024) void k_gmaxT(const f16* __restrict__ lfT,
                                                float* __restrict__ gmax8)
{
  __shared__ float red[8][128];
  const int b = blockIdx.x >> 3, h = blockIdx.x & 7;
  const int c = threadIdx.x & 127, r = threadIdx.x >> 7;   // r: 0..7
  const f16* p = lfT + (long)b*NPT*128;
  float m = -1e30f;
  for (int n = h*256 + r; n < (h+1)*256; n += 8) m = fmaxf(m, (float)p[(long)n*128 + c]);
  red[r][c] = m; __syncthreads();
  if (threadIdx.x < 128){
    float mm = red[0][c];
    #pragma unroll
    for (int j=1;j<8;++j) mm = fmaxf(mm, red[j][c]);
    gmax8[((long)b*8 + h)*128 + c] = mm;
  }
}

// gc[b][o] = b0[o] + sum_c w0[o][128+c]*gmax[b][c]; gmax folded from 8 partials
__global__ __launch_bounds__(128) void k_gvec(const float* __restrict__ w0,
                                              const float* __restrict__ b0,
                                              const float* __restrict__ gmax8,
                                              float* __restrict__ gc)
{
  const int b = blockIdx.x, o = threadIdx.x;
  __shared__ float g[128];
  float mm = gmax8[((long)b*8 + 0)*128 + o];
  #pragma unroll
  for (int h=1;h<8;++h) mm = fmaxf(mm, gmax8[((long)b*8 + h)*128 + o]);
  g[o] = mm; __syncthreads();
  float acc = b0[o];
  for (int c = 0; c < 128; ++c) acc = fmaf(w0[o*256 + 128 + c], g[c], acc);
  gc[b*128+o] = acc;
}

// ---------------------------------------------------------------------------
// SA epilogue GEMM with FUSED partial merge (NSEG=2):
// xr[n][c] = (p0+p1)*inv computed inline from xrpart/cspart.
// cat[b][n][Lcol+o] = x[n][o] + relu(g'*(wt@(x-xr))+..). grid (32,2,B).
// ---------------------------------------------------------------------------
__global__ __launch_bounds__(256) void k_safin2(
    const f16* __restrict__ Wt, const float* __restrict__ bt,
    const float* __restrict__ g, const float* __restrict__ be,
    const f16* __restrict__ xT,
    const f16* __restrict__ xrpart, const float* __restrict__ cspart,
    f16* __restrict__ cat, int Lcol)
{
  __shared__ __align__(16) f16 Xs[64][72];
  __shared__ __align__(16) f16 Wsh[64][72];
  const int b  = blockIdx.z;
  const int n0 = blockIdx.x * 64;
  const int o0 = blockIdx.y * 64;
  const int tid = threadIdx.x, lane = tid & 63, w = tid >> 6;
  const int lr = lane & 15, lg = lane >> 4;
  const int wn = w>>1, wo = w&1;
  const f16* xb = xT + (long)b*NPT*128;
  f32x4 acc[2][2];
  #pragma unroll
  for (int ni=0;ni<2;++ni){ acc[ni][0]=(f32x4){0,0,0,0}; acc[ni][1]=(f32x4){0,0,0,0}; }

  for (int k0=0; k0<128; k0+=64){
    #pragma unroll
    for (int gidx = tid; gidx < 512; gidx += 256){
      int r = gidx>>3, s = gidx&7;
      const long nn = n0 + r;
      const long r0 = ((long)b*NSEG + 0)*NPT + nn;
      const long r1 = r0 + NPT;
      const float inv = 1.f/(1e-9f + cspart[r0] + cspart[r1]);
      f16x8 xa = *(const f16x8*)(xb + nn*128 + k0 + s*8);
      f16x8 p0 = *(const f16x8*)(xrpart + r0*128 + k0 + s*8);
      f16x8 p1 = *(const f16x8*)(xrpart + r1*128 + k0 + s*8);
      f16x8 xs;
      #pragma unroll
      for (int j=0;j<8;++j)
        xs[j] = (f16)((float)xa[j] - ((float)p0[j] + (float)p1[j]) * inv);
      *(f16x8*)&Xs[r][s*8] = xs;
      *(float4*)&Wsh[r][s*8] = *(const float4*)(Wt + (long)(o0+r)*128 + k0 + s*8);
    }
    __syncthreads();
    #pragma unroll
    for (int ks=0; ks<2; ++ks){
      f16x8 a[2], bf[2];
      #pragma unroll
      for (int ni=0;ni<2;++ni) a[ni] = *(const f16x8*)&Xs[wn*32 + ni*16 + lr][ks*32 + lg*8];
      #pragma unroll
      for (int oi=0;oi<2;++oi) bf[oi] = *(const f16x8*)&Wsh[wo*32 + oi*16 + lr][ks*32 + lg*8];
      #pragma unroll
      for (int ni=0;ni<2;++ni)
        #pragma unroll
        for (int oi=0;oi<2;++oi) acc[ni][oi] = mfma16(a[ni], bf[oi], acc[ni][oi]);
    }
    __syncthreads();
  }
  const float bnsc = rsqrtf(1.f + 1e-5f);
  #pragma unroll
  for (int ni=0;ni<2;++ni)
    #pragma unroll
    for (int oi=0;oi<2;++oi){
      const int oc = o0 + wo*32 + oi*16 + lr;
      const float bti = bt[oc], gi = g[oc]*bnsc, bei = be[oc];
      #pragma unroll
      for (int i=0;i<4;++i){
        const int nn = n0 + wn*32 + ni*16 + lg*4 + i;
        float t = acc[ni][oi][i] + bti;
        float val = fmaxf(fmaf(gi, t, bei), 0.f);
        float res = (float)xb[(long)nn*128 + oc];
        cat[(long)b*NPT*384 + (long)nn*384 + Lcol + oc] = (f16)(res + val);
      }
    }
}

__global__ __launch_bounds__(256) void k_maxfinal(const float* __restrict__ part,
                                                  float* __restrict__ out)
{
  const int t = blockIdx.x*256 + threadIdx.x;   // 0..16383
  float m = -1e30f;
  #pragma unroll
  for (int j=0;j<16;++j) m = fmaxf(m, part[(long)t*16 + j]);
  out[t] = m;
}

// ---------------------------------------------------------------------------
extern "C" void kernel_launch(void* const* d_in, const int* in_sizes, int n_in,
                              void* d_out, int out_size, void* d_ws, size_t ws_size,
                              hipStream_t stream)
{
  const float* in   = (const float*)d_in[0];
  const float* m1w0 = (const float*)d_in[1];
  const float* m1b0 = (const float*)d_in[2];
  const float* m1w1 = (const float*)d_in[3];
  const float* m1b1 = (const float*)d_in[4];
  const float* m2w0 = (const float*)d_in[5];
  const float* m2b0 = (const float*)d_in[6];
  const float* m2w1 = (const float*)d_in[7];
  const float* m2b1 = (const float*)d_in[8];
  const float* m3w0 = (const float*)d_in[9];
  const float* m3b0 = (const float*)d_in[10];
  const float* m3w1 = (const float*)d_in[11];
  const float* m3b1 = (const float*)d_in[12];

  // ws layout (halfs)
  f16* ws16 = (f16*)d_ws;
  f16* W16  = ws16;                       // 880,640
  f16* lfT  = ws16 + 880640;              // [B][N][128]
  f16* xT   = ws16 + 5074944;             // [B][N][128]
  f16* qT   = ws16 + 9269248;             // [B][N][32]
  f16* vbuf = ws16 + 10317824;            // [B][128][N]
  f16* xrT  = ws16 + 14512128;            // [B][N][128] (mlp2 features)
  f16* hT   = ws16 + 18706432;            // [B][N][512] (mlp3 hidden)
  f16* xrpart = hT;                       // [B*NSEG][N][128] — aliases hT (dead during SA)
  f16* catT = ws16 + 35483648;            // [B][N][384]
  float* fb = (float*)(ws16 + 48066560);
  float* ralpha = fb;                     // [B,N] (folded rmax+log(rsum))
  float* gc     = fb + 67584;             // [B,128]
  float* part   = fb + 69632;             // [B,1024,16]
  float* cspart = fb + 593920;            // [B*NSEG][N]
  float* gmax8  = fb + 659456;            // [B][8][128]
  float* mxpart = fb + 675840;            // [B*NRS][N]
  float* smpart = fb + 806912;            // [B*NRS][N]

  const dim3 blk(256);

  k_wconv<<<dim3((WTOT+255)/256), blk, 0, stream>>>(
      m1w1, m2w0, m2w1, m3w0, m3w1,
      (const float*)d_in[13], (const float*)d_in[14], (const float*)d_in[16],
      (const float*)d_in[20], (const float*)d_in[21], (const float*)d_in[23],
      (const float*)d_in[27], (const float*)d_in[28], (const float*)d_in[30],
      W16);

  // mlp1 (fused l0+l1)
  k_mlp1f<<<dim3(32,NBAT), blk, 0, stream>>>(in, m1w0, m1b0, W16+OFF_M1W1, m1b1, lfT);
  // global max (widened) + mlp2 (fused l0+l1) -> features in xrT
  k_gmaxT<<<dim3(NBAT*8), dim3(1024), 0, stream>>>(lfT, gmax8);
  k_gvec<<<dim3(NBAT), dim3(128), 0, stream>>>(m2w0, m2b0, gmax8, gc);
  k_mlp2f<<<dim3(32,NBAT), blk, 0, stream>>>(
      W16+OFF_M2W0A, gc, W16+OFF_M2W1, m2b1, lfT, xrT);

  // 3 SA layers (addT, qgemm, pmerge fused away; rowstats m-split 4-way)
  for (int L = 0; L < 3; ++L){
    const float* bv = (const float*)d_in[13 + L*7 + 2];
    const float* bt = (const float*)d_in[13 + L*7 + 4];
    const float* gg = (const float*)d_in[13 + L*7 + 5];
    const float* be = (const float*)d_in[13 + L*7 + 6];
    const f16* wq16 = W16 + OFF_SA + L*SA_STRIDE;
    const f16* wv16 = wq16 + 4096;
    const f16* wt16 = wq16 + 20480;

    const f16* prev = (L==0) ? xrT : (catT + (long)(L-1)*128);
    const int  prs  = (L==0) ? 128 : 384;

    k_vqgemmF<<<dim3(32,2,NBAT), blk, 0, stream>>>(
        wv16, bv, wq16, prev, prs, lfT, vbuf, xT, qT);
    k_rowstats2<<<dim3(32,NRS,NBAT), blk, 0, stream>>>(qT, mxpart, smpart);
    k_rsfold<<<dim3(NBAT*NPT/256), blk, 0, stream>>>(mxpart, smpart, ralpha);
    k_pass2p<<<dim3(32,NSEG,NBAT), blk, 0, stream>>>(qT, vbuf, ralpha, xrpart, cspart);
    k_safin2<<<dim3(32,2,NBAT), blk, 0, stream>>>(
        wt16, bt, gg, be, xT, xrpart, cspart, catT, L*128);
  }

  // mlp3: layer0 (384->512 relu) 128x128 tile, layer1 fused-max 128x128
  gemm128<true><<<dim3(16,4,NBAT), blk, 0, stream>>>(
      W16+OFF_M3W0, m3b0, catT, 384, hT, 512, 384);
  k_gemmax128<<<dim3(16,8,NBAT), blk, 0, stream>>>(W16+OFF_M3W1, m3b1, hT, part);
  k_maxfinal<<<dim3(64), blk, 0, stream>>>(part, (float*)d_out);
}